// Round 6
// baseline (70.162 us; speedup 1.0000x reference)
//
#include <hip/hip_runtime.h>

#define Bn 8
#define Hn 128
#define Wn 128
#define Cn 64
#define Dn 16
#define NS 26            // 5*5 neighbors + self
#define NPX (Bn * Hn * Wn)    // 131072 pixels

// ws layout: [0,16KB) packed f16 weights | wsQ uint4[8][NPX] | wsK uint4[8][NPX]
// plane index = head*2 + dhalf ; each uint4 = 8 f16 = half of d
#define WS_WP_U32   4096
#define WS_Q_OFF_B  16384
#define WS_K_OFF_B  (WS_Q_OFF_B + 8 * NPX * 16)
#define WS_NEEDED   ((size_t)WS_K_OFF_B + (size_t)8 * NPX * 16)

typedef _Float16 h2 __attribute__((ext_vector_type(2)));

__device__ __forceinline__ unsigned int pkf16(float a, float b) {
    return __builtin_bit_cast(unsigned int, __builtin_amdgcn_cvt_pkrtz(a, b));
}
__device__ __forceinline__ float dot2(unsigned int a, unsigned int b, float c) {
    return __builtin_amdgcn_fdot2(__builtin_bit_cast(h2, a),
                                  __builtin_bit_cast(h2, b), c, false);
}

// ---- pack W into c-pair-major f16x2: wp[t][h][m][d], m = c/2 ----
__global__ void pack_weights(const float* __restrict__ Wm,
                             const float* __restrict__ Wr,
                             unsigned int* __restrict__ wp) {
    const int idx = blockIdx.x * 256 + threadIdx.x;
    if (idx < 2 * 4 * 32 * Dn) {
        const int t = idx >> 11;
        const int r = idx & 2047;
        const int h = r >> 9;
        const int m = (r >> 4) & 31;
        const int d = r & 15;
        const float* W = t ? Wr : Wm;
        wp[idx] = pkf16(W[h * (Cn * Dn) + (2 * m) * Dn + d],
                        W[h * (Cn * Dn) + (2 * m + 1) * Dn + d]);
    }
}

__device__ __forceinline__ void proj16(const float4* sIn, int lane,
                                       const unsigned int* wh, float* acc) {
#pragma unroll
    for (int c4 = 0; c4 < 16; ++c4) {
        const float4 v = sIn[lane * 17 + c4];
        const unsigned int a01 = pkf16(v.x, v.y);
        const unsigned int a23 = pkf16(v.z, v.w);
        const unsigned int* w0 = wh + (2 * c4) * Dn;
        const unsigned int* w1 = wh + (2 * c4 + 1) * Dn;
#pragma unroll
        for (int d = 0; d < Dn; ++d) acc[d] = dot2(a01, w0[d], acc[d]);
#pragma unroll
        for (int d = 0; d < Dn; ++d) acc[d] = dot2(a23, w1[d], acc[d]);
    }
}

// ---- pass 1: q,k projections, once per px-head; planar d-half output ----
__global__ __launch_bounds__(256, 3)
void proj_qk(const float* __restrict__ mainp,
             const float* __restrict__ refp,
             const unsigned int* __restrict__ wp,
             uint4* __restrict__ wsQ,
             uint4* __restrict__ wsK)
{
    __shared__ float4 sIn[64 * 17];   // 17408 B

    const int tid  = threadIdx.x;
    const int lane = tid & 63;
    const int wv   = tid >> 6;
    const int head = __builtin_amdgcn_readfirstlane(wv);
    const int pxbase = blockIdx.x * 64;

    const unsigned int* wmh = wp + head * (32 * Dn);
    const unsigned int* wrh = wp + 2048 + head * (32 * Dn);

    // stage main tile (64 px x 64 ch = 16 KB), coalesced
    const float4* mp4 = (const float4*)mainp + (size_t)pxbase * 16;
#pragma unroll
    for (int t = 0; t < 4; ++t) {
        const int idx = t * 256 + tid;
        sIn[(idx >> 4) * 17 + (idx & 15)] = mp4[idx];
    }
    __syncthreads();

    float acc[Dn];
#pragma unroll
    for (int d = 0; d < Dn; ++d) acc[d] = 0.f;
    proj16(sIn, lane, wmh, acc);
    wsQ[(head * 2 + 0) * NPX + pxbase + lane] =
        make_uint4(pkf16(acc[0], acc[1]),  pkf16(acc[2], acc[3]),
                   pkf16(acc[4], acc[5]),  pkf16(acc[6], acc[7]));
    wsQ[(head * 2 + 1) * NPX + pxbase + lane] =
        make_uint4(pkf16(acc[8], acc[9]),  pkf16(acc[10], acc[11]),
                   pkf16(acc[12], acc[13]), pkf16(acc[14], acc[15]));

    __syncthreads();   // done reading main tile
    const float4* rp4 = (const float4*)refp + (size_t)pxbase * 16;
#pragma unroll
    for (int t = 0; t < 4; ++t) {
        const int idx = t * 256 + tid;
        sIn[(idx >> 4) * 17 + (idx & 15)] = rp4[idx];
    }
    __syncthreads();

#pragma unroll
    for (int d = 0; d < Dn; ++d) acc[d] = 0.f;
    proj16(sIn, lane, wrh, acc);
    wsK[(head * 2 + 0) * NPX + pxbase + lane] =
        make_uint4(pkf16(acc[0], acc[1]),  pkf16(acc[2], acc[3]),
                   pkf16(acc[4], acc[5]),  pkf16(acc[6], acc[7]));
    wsK[(head * 2 + 1) * NPX + pxbase + lane] =
        make_uint4(pkf16(acc[8], acc[9]),  pkf16(acc[10], acc[11]),
                   pkf16(acc[12], acc[13]), pkf16(acc[14], acc[15]));
}

// ---- pass 2: scores straight from global (L1/L2), softmax, head-mean ----
// 4 waves = 4 heads over the same 8x8 tile. No LDS in the load/compute path;
// 13.3 KB combine buffer only -> 4+ blocks/CU under the 64-KB regime.
__global__ __launch_bounds__(256, 4)
void attn_scores(const uint4* __restrict__ wsQ,
                 const uint4* __restrict__ wsK,
                 float* __restrict__ out)
{
    __shared__ unsigned int sP[4 * 64 * 13];   // u16-quantized attn, 13312 B

    const int tid  = threadIdx.x;
    const int lane = tid & 63;
    const int wv   = tid >> 6;
    const int head = __builtin_amdgcn_readfirstlane(wv);
    const int b    = blockIdx.z;
    const int y0   = blockIdx.y * 8;
    const int x0   = blockIdx.x * 8;
    const int pr   = lane >> 3;
    const int pc   = lane & 7;
    const int y    = y0 + pr;
    const int x    = x0 + pc;
    const int pxf  = (b * Hn + y) * Wn + x;

    const uint4* klo = wsK + (head * 2 + 0) * NPX;
    const uint4* khi = wsK + (head * 2 + 1) * NPX;

    const uint4 qa = wsQ[(head * 2 + 0) * NPX + pxf];
    const uint4 qb = wsQ[(head * 2 + 1) * NPX + pxf];

    // 0/1 float validity masks (zero-padded-k semantics: oob score == 0)
    float rvf[5], cvf[5];
#pragma unroll
    for (int t = 0; t < 5; ++t) {
        rvf[t] = ((unsigned)(y + t - 2) < (unsigned)Hn) ? 1.f : 0.f;
        cvf[t] = ((unsigned)(x + t - 2) < (unsigned)Wn) ? 1.f : 0.f;
    }

    float sc[NS];
#pragma unroll
    for (int di = 0; di < 5; ++di) {
        const int rb = pxf + (di - 2) * Wn - 2;
        uint4 kl[5], kh[5];
#pragma unroll
        for (int dj = 0; dj < 5; ++dj) {
            int idx = rb + dj;
            idx = idx < 0 ? 0 : (idx > NPX - 1 ? NPX - 1 : idx);   // in-buffer clamp
            kl[dj] = klo[idx];
            kh[dj] = khi[idx];
        }
#pragma unroll
        for (int dj = 0; dj < 5; ++dj) {
            float s0 = dot2(qa.x, kl[dj].x, 0.f);
            float s1 = dot2(qb.x, kh[dj].x, 0.f);
            s0 = dot2(qa.y, kl[dj].y, s0);
            s1 = dot2(qb.y, kh[dj].y, s1);
            s0 = dot2(qa.z, kl[dj].z, s0);
            s1 = dot2(qb.z, kh[dj].z, s1);
            s0 = dot2(qa.w, kl[dj].w, s0);
            s1 = dot2(qb.w, kh[dj].w, s1);
            sc[di * 5 + dj] = (s0 + s1) * (rvf[di] * cvf[dj]);
        }
    }
    {   // self score q.q
        float s0 = dot2(qa.x, qa.x, 0.f);
        float s1 = dot2(qb.x, qb.x, 0.f);
        s0 = dot2(qa.y, qa.y, s0);
        s1 = dot2(qb.y, qb.y, s1);
        s0 = dot2(qa.z, qa.z, s0);
        s1 = dot2(qb.z, qb.z, s1);
        s0 = dot2(qa.w, qa.w, s0);
        s1 = dot2(qb.w, qb.w, s1);
        sc[25] = s0 + s1;
    }

    // softmax
    float mx = sc[0];
#pragma unroll
    for (int i = 1; i < NS; ++i) mx = fmaxf(mx, sc[i]);
    float ssum = 0.f;
#pragma unroll
    for (int i = 0; i < NS; ++i) { sc[i] = __expf(sc[i] - mx); ssum += sc[i]; }
    const float inv = 1.0f / ssum;
#pragma unroll
    for (int i = 0; i < NS; ++i) sc[i] *= inv;

    // u16 fixed-point attn -> LDS [head][px][13 pair-words]
    {
        unsigned int* myrow = sP + (wv * 64 + lane) * 13;
#pragma unroll
        for (int j = 0; j < 13; ++j) {
            const unsigned int ulo = (unsigned int)(sc[2 * j] * 65535.f + 0.5f);
            const unsigned int uhi = (unsigned int)(sc[2 * j + 1] * 65535.f + 0.5f);
            myrow[j] = ulo | (uhi << 16);
        }
    }
    __syncthreads();

    // head-mean + store (float2, fully coalesced within each tile row)
    const size_t ob = ((size_t)(b * Hn + y0) * Wn + x0) * NS;
    for (int idx = tid; idx < 64 * 13; idx += 256) {
        const int px = idx / 13;
        const int p  = idx - px * 13;
        const unsigned int u0 = sP[(0 * 64 + px) * 13 + p];
        const unsigned int u1 = sP[(1 * 64 + px) * 13 + p];
        const unsigned int u2 = sP[(2 * 64 + px) * 13 + p];
        const unsigned int u3 = sP[(3 * 64 + px) * 13 + p];
        const float lo = (float)((u0 & 0xffffu) + (u1 & 0xffffu) +
                                 (u2 & 0xffffu) + (u3 & 0xffffu));
        const float hi = (float)((u0 >> 16) + (u1 >> 16) + (u2 >> 16) + (u3 >> 16));
        const float k = 1.f / (4.f * 65535.f);
        const int r = px >> 3;
        const int c = px & 7;
        *(float2*)(out + ob + (size_t)r * (Wn * NS) + c * NS + 2 * p) =
            make_float2(lo * k, hi * k);
    }
}

// ================= fallback: R4 monolithic (needs only 16 KB ws) ==========
#define TILE 8
#define HALO 12
#define NHALO (HALO * HALO)
#define PXW 36
__global__ __launch_bounds__(256, 4)
void local_attn_fused_r4(const float* __restrict__ mainp,
                         const float* __restrict__ refp,
                         const unsigned int* __restrict__ wp,
                         float* __restrict__ out)
{
    __shared__ unsigned int sK[NHALO * PXW];
    const int tid  = threadIdx.x;
    const int lane = tid & 63;
    const int wv   = tid >> 6;
    const int head = __builtin_amdgcn_readfirstlane(wv);
    const int b    = blockIdx.z;
    const int y0   = blockIdx.y * TILE;
    const int x0   = blockIdx.x * TILE;
    const unsigned int* wmh = wp + head * (32 * Dn);
    const unsigned int* wrh = wp + 2048 + head * (32 * Dn);
    for (int p = lane; p < NHALO; p += 64) {
        const int hr = p / HALO;
        const int hc = p - hr * HALO;
        const int gy = y0 - 2 + hr;
        const int gx = x0 - 2 + hc;
        float acc[Dn];
#pragma unroll
        for (int d = 0; d < Dn; ++d) acc[d] = 0.f;
        if ((unsigned)gy < (unsigned)Hn && (unsigned)gx < (unsigned)Wn) {
            const float4* rp4 = (const float4*)(refp + (((size_t)b * Hn + gy) * Wn + gx) * Cn);
#pragma unroll
            for (int c4 = 0; c4 < Cn / 4; ++c4) {
                const float4 rv = rp4[c4];
                const unsigned int r01 = pkf16(rv.x, rv.y);
                const unsigned int r23 = pkf16(rv.z, rv.w);
                const unsigned int* w0 = wrh + (2 * c4) * Dn;
                const unsigned int* w1 = wrh + (2 * c4 + 1) * Dn;
#pragma unroll
                for (int d = 0; d < Dn; ++d) acc[d] = dot2(r01, w0[d], acc[d]);
#pragma unroll
                for (int d = 0; d < Dn; ++d) acc[d] = dot2(r23, w1[d], acc[d]);
            }
        }
        unsigned int pk[8];
#pragma unroll
        for (int j = 0; j < 8; ++j) pk[j] = pkf16(acc[2 * j], acc[2 * j + 1]);
        unsigned int* dst = sK + p * PXW + head * 8;
        *(uint4*)(dst)     = make_uint4(pk[0], pk[1], pk[2], pk[3]);
        *(uint4*)(dst + 4) = make_uint4(pk[4], pk[5], pk[6], pk[7]);
    }
    const int pr = lane >> 3;
    const int pc = lane & 7;
    const float4* mp4 = (const float4*)(mainp + (((size_t)b * Hn + (y0 + pr)) * Wn + (x0 + pc)) * Cn);
    float q[Dn];
#pragma unroll
    for (int d = 0; d < Dn; ++d) q[d] = 0.f;
#pragma unroll
    for (int c4 = 0; c4 < Cn / 4; ++c4) {
        const float4 mv = mp4[c4];
        const unsigned int m01 = pkf16(mv.x, mv.y);
        const unsigned int m23 = pkf16(mv.z, mv.w);
        const unsigned int* w0 = wmh + (2 * c4) * Dn;
        const unsigned int* w1 = wmh + (2 * c4 + 1) * Dn;
#pragma unroll
        for (int d = 0; d < Dn; ++d) q[d] = dot2(m01, w0[d], q[d]);
#pragma unroll
        for (int d = 0; d < Dn; ++d) q[d] = dot2(m23, w1[d], q[d]);
    }
    unsigned int qh[8];
#pragma unroll
    for (int j = 0; j < 8; ++j) qh[j] = pkf16(q[2 * j], q[2 * j + 1]);
    __syncthreads();
    float sc[NS];
#pragma unroll
    for (int di = 0; di < 5; ++di) {
#pragma unroll
        for (int dj = 0; dj < 5; ++dj) {
            const int h = (pr + di) * HALO + (pc + dj);
            const unsigned int* src = sK + h * PXW + head * 8;
            const uint4 ka = *(const uint4*)(src);
            const uint4 kb = *(const uint4*)(src + 4);
            float s;
            s = dot2(qh[0], ka.x, 0.f);
            s = dot2(qh[1], ka.y, s);
            s = dot2(qh[2], ka.z, s);
            s = dot2(qh[3], ka.w, s);
            s = dot2(qh[4], kb.x, s);
            s = dot2(qh[5], kb.y, s);
            s = dot2(qh[6], kb.z, s);
            s = dot2(qh[7], kb.w, s);
            sc[di * 5 + dj] = s;
        }
    }
    {
        float s = q[0] * q[0];
#pragma unroll
        for (int d = 1; d < Dn; ++d) s = fmaf(q[d], q[d], s);
        sc[25] = s;
    }
    float mx = sc[0];
#pragma unroll
    for (int i = 1; i < NS; ++i) mx = fmaxf(mx, sc[i]);
    float ssum = 0.f;
#pragma unroll
    for (int i = 0; i < NS; ++i) { sc[i] = __expf(sc[i] - mx); ssum += sc[i]; }
    const float inv = 1.0f / ssum;
#pragma unroll
    for (int i = 0; i < NS; ++i) sc[i] *= inv;
    __syncthreads();
    {
        unsigned int* myrow = sK + (wv * 64 + lane) * 14;
#pragma unroll
        for (int j = 0; j < 13; ++j) myrow[j] = pkf16(sc[2 * j], sc[2 * j + 1]);
    }
    __syncthreads();
    const unsigned short* sA = (const unsigned short*)sK;
    const size_t obase = (((size_t)b * Hn + y0) * Wn + x0) * NS;
    for (int idx = tid; idx < TILE * TILE * NS; idx += 256) {
        const int r   = idx / (TILE * NS);
        const int t   = idx - r * (TILE * NS);
        const int c   = t / NS;
        const int i   = t - c * NS;
        const int ppx = r * TILE + c;
        float acc = 0.f;
#pragma unroll
        for (int h = 0; h < 4; ++h)
            acc += (float)__builtin_bit_cast(_Float16, sA[(h * 64 + ppx) * 28 + i]);
        out[obase + (size_t)r * (Wn * NS) + t] = 0.25f * acc;
    }
}

extern "C" void kernel_launch(void* const* d_in, const int* in_sizes, int n_in,
                              void* d_out, int out_size, void* d_ws, size_t ws_size,
                              hipStream_t stream) {
    (void)in_sizes; (void)n_in; (void)out_size;
    const float* mainp = (const float*)d_in[0];
    const float* refp  = (const float*)d_in[1];
    const float* Wm    = (const float*)d_in[2];
    const float* Wr    = (const float*)d_in[3];
    unsigned int* wpk  = (unsigned int*)d_ws;
    float* out = (float*)d_out;

    pack_weights<<<16, 256, 0, stream>>>(Wm, Wr, wpk);
    if (ws_size >= WS_NEEDED) {
        uint4* wsQ = (uint4*)((char*)d_ws + WS_Q_OFF_B);
        uint4* wsK = (uint4*)((char*)d_ws + WS_K_OFF_B);
        proj_qk<<<NPX / 64, 256, 0, stream>>>(mainp, refp, wpk, wsQ, wsK);
        dim3 grid2(Wn / 8, Hn / 8, Bn);                // 16 x 16 x 8 = 2048
        attn_scores<<<grid2, 256, 0, stream>>>(wsQ, wsK, out);
    } else {
        dim3 grid2(Wn / TILE, Hn / TILE, Bn);
        local_attn_fused_r4<<<grid2, 256, 0, stream>>>(mainp, refp, wpk, out);
    }
}

// Round 7
// 57.066 us; speedup vs baseline: 1.2295x; 1.2295x over previous
//
#include <hip/hip_runtime.h>

#define Bn 8
#define Hn 128
#define Wn 128
#define Cn 64
#define Dn 16
#define NS 26            // 5*5 neighbors + self
#define NPX (Bn * Hn * Wn)    // 131072 pixels

// ws layout: [0,16KB) packed f16 weights | wsQ uint4[8][NPX] | wsK uint4[8][NPX]
// plane index = head*2 + dhalf ; each uint4 = 8 f16 = half of d
#define WS_WP_U32   4096
#define WS_Q_OFF_B  16384
#define WS_K_OFF_B  (WS_Q_OFF_B + 8 * NPX * 16)
#define WS_NEEDED   ((size_t)WS_K_OFF_B + (size_t)8 * NPX * 16)

typedef _Float16 h2 __attribute__((ext_vector_type(2)));

__device__ __forceinline__ unsigned int pkf16(float a, float b) {
    return __builtin_bit_cast(unsigned int, __builtin_amdgcn_cvt_pkrtz(a, b));
}
__device__ __forceinline__ float dot2(unsigned int a, unsigned int b, float c) {
    return __builtin_amdgcn_fdot2(__builtin_bit_cast(h2, a),
                                  __builtin_bit_cast(h2, b), c, false);
}

// ---- pack W into c-pair-major f16x2: wp[t][h][m][d], m = c/2 ----
__global__ void pack_weights(const float* __restrict__ Wm,
                             const float* __restrict__ Wr,
                             unsigned int* __restrict__ wp) {
    const int idx = blockIdx.x * 256 + threadIdx.x;
    if (idx < 2 * 4 * 32 * Dn) {
        const int t = idx >> 11;
        const int r = idx & 2047;
        const int h = r >> 9;
        const int m = (r >> 4) & 31;
        const int d = r & 15;
        const float* W = t ? Wr : Wm;
        wp[idx] = pkf16(W[h * (Cn * Dn) + (2 * m) * Dn + d],
                        W[h * (Cn * Dn) + (2 * m + 1) * Dn + d]);
    }
}

__device__ __forceinline__ void proj16(const float4* sIn, int lane,
                                       const unsigned int* wh, float* acc) {
#pragma unroll
    for (int c4 = 0; c4 < 16; ++c4) {
        const float4 v = sIn[lane * 17 + c4];
        const unsigned int a01 = pkf16(v.x, v.y);
        const unsigned int a23 = pkf16(v.z, v.w);
        const unsigned int* w0 = wh + (2 * c4) * Dn;
        const unsigned int* w1 = wh + (2 * c4 + 1) * Dn;
#pragma unroll
        for (int d = 0; d < Dn; ++d) acc[d] = dot2(a01, w0[d], acc[d]);
#pragma unroll
        for (int d = 0; d < Dn; ++d) acc[d] = dot2(a23, w1[d], acc[d]);
    }
}

// ---- pass 1: q,k projections, once per px-head; planar d-half output ----
__global__ __launch_bounds__(256, 3)
void proj_qk(const float* __restrict__ mainp,
             const float* __restrict__ refp,
             const unsigned int* __restrict__ wp,
             uint4* __restrict__ wsQ,
             uint4* __restrict__ wsK)
{
    __shared__ float4 sIn[64 * 17];   // 17408 B

    const int tid  = threadIdx.x;
    const int lane = tid & 63;
    const int wv   = tid >> 6;
    const int head = __builtin_amdgcn_readfirstlane(wv);
    const int pxbase = blockIdx.x * 64;

    const unsigned int* wmh = wp + head * (32 * Dn);
    const unsigned int* wrh = wp + 2048 + head * (32 * Dn);

    // stage main tile (64 px x 64 ch = 16 KB), coalesced
    const float4* mp4 = (const float4*)mainp + (size_t)pxbase * 16;
#pragma unroll
    for (int t = 0; t < 4; ++t) {
        const int idx = t * 256 + tid;
        sIn[(idx >> 4) * 17 + (idx & 15)] = mp4[idx];
    }
    __syncthreads();

    float acc[Dn];
#pragma unroll
    for (int d = 0; d < Dn; ++d) acc[d] = 0.f;
    proj16(sIn, lane, wmh, acc);
    wsQ[(head * 2 + 0) * NPX + pxbase + lane] =
        make_uint4(pkf16(acc[0], acc[1]),  pkf16(acc[2], acc[3]),
                   pkf16(acc[4], acc[5]),  pkf16(acc[6], acc[7]));
    wsQ[(head * 2 + 1) * NPX + pxbase + lane] =
        make_uint4(pkf16(acc[8], acc[9]),  pkf16(acc[10], acc[11]),
                   pkf16(acc[12], acc[13]), pkf16(acc[14], acc[15]));

    __syncthreads();   // done reading main tile
    const float4* rp4 = (const float4*)refp + (size_t)pxbase * 16;
#pragma unroll
    for (int t = 0; t < 4; ++t) {
        const int idx = t * 256 + tid;
        sIn[(idx >> 4) * 17 + (idx & 15)] = rp4[idx];
    }
    __syncthreads();

#pragma unroll
    for (int d = 0; d < Dn; ++d) acc[d] = 0.f;
    proj16(sIn, lane, wrh, acc);
    wsK[(head * 2 + 0) * NPX + pxbase + lane] =
        make_uint4(pkf16(acc[0], acc[1]),  pkf16(acc[2], acc[3]),
                   pkf16(acc[4], acc[5]),  pkf16(acc[6], acc[7]));
    wsK[(head * 2 + 1) * NPX + pxbase + lane] =
        make_uint4(pkf16(acc[8], acc[9]),  pkf16(acc[10], acc[11]),
                   pkf16(acc[12], acc[13]), pkf16(acc[14], acc[15]));
}

// ---- pass 2: LDS-staged scores, planar conflict-free layout ----
// 4 waves = 4 heads over one 8x8 tile. LDS [head*2+half][192] x 16B = 24.6 KB
// (192 = 144 halo px rounded up; slack unused). Zero-staged SAME padding.
__global__ __launch_bounds__(256, 4)
void attn_scores(const uint4* __restrict__ wsQ,
                 const uint4* __restrict__ wsK,
                 float* __restrict__ out)
{
    __shared__ uint4 sKp[8][192];     // 24576 B; reused for head-combine

    const int tid  = threadIdx.x;
    const int lane = tid & 63;
    const int wv   = tid >> 6;
    const int head = __builtin_amdgcn_readfirstlane(wv);
    const int b    = blockIdx.z;
    const int y0   = blockIdx.y * 8;
    const int x0   = blockIdx.x * 8;
    const int pr   = lane >> 3;
    const int pc   = lane & 7;
    const int pxf  = (b * Hn + (y0 + pr)) * Wn + (x0 + pc);

    const uint4* klo = wsK + (head * 2 + 0) * NPX;
    const uint4* khi = wsK + (head * 2 + 1) * NPX;

    // ---- stage my head's 12x12 k halo; oob -> zero (SAME semantics) ----
#pragma unroll
    for (int it = 0; it < 3; ++it) {
        const int p = it * 64 + lane;
        if (p < 144) {
            const int hr = p / 12;
            const int hc = p - hr * 12;
            const int gy = y0 - 2 + hr;
            const int gx = x0 - 2 + hc;
            uint4 lo = make_uint4(0, 0, 0, 0), hi = make_uint4(0, 0, 0, 0);
            if ((unsigned)gy < (unsigned)Hn && (unsigned)gx < (unsigned)Wn) {
                const int g = (b * Hn + gy) * Wn + gx;
                lo = klo[g];
                hi = khi[g];
            }
            sKp[head * 2 + 0][p] = lo;
            sKp[head * 2 + 1][p] = hi;
        }
    }

    // my q (pre-barrier: overlaps staging)
    const uint4 qa = wsQ[(head * 2 + 0) * NPX + pxf];
    const uint4 qb = wsQ[(head * 2 + 1) * NPX + pxf];

    __syncthreads();

    // ---- 25 neighbor scores: per di-row, 10 independent b128 reads then
    // 80 dot2 with dual accumulators ----
    const uint4* plo = &sKp[head * 2 + 0][0];
    const uint4* phi = &sKp[head * 2 + 1][0];
    float sc[NS];
#pragma unroll
    for (int di = 0; di < 5; ++di) {
        const int hb = (pr + di) * 12 + pc;
        uint4 kl[5], kh[5];
#pragma unroll
        for (int dj = 0; dj < 5; ++dj) { kl[dj] = plo[hb + dj]; kh[dj] = phi[hb + dj]; }
#pragma unroll
        for (int dj = 0; dj < 5; ++dj) {
            float s0 = dot2(qa.x, kl[dj].x, 0.f);
            float s1 = dot2(qb.x, kh[dj].x, 0.f);
            s0 = dot2(qa.y, kl[dj].y, s0);
            s1 = dot2(qb.y, kh[dj].y, s1);
            s0 = dot2(qa.z, kl[dj].z, s0);
            s1 = dot2(qb.z, kh[dj].z, s1);
            s0 = dot2(qa.w, kl[dj].w, s0);
            s1 = dot2(qb.w, kh[dj].w, s1);
            sc[di * 5 + dj] = s0 + s1;
        }
    }
    {   // self score q.q
        float s0 = dot2(qa.x, qa.x, 0.f);
        float s1 = dot2(qb.x, qb.x, 0.f);
        s0 = dot2(qa.y, qa.y, s0);
        s1 = dot2(qb.y, qb.y, s1);
        s0 = dot2(qa.z, qa.z, s0);
        s1 = dot2(qb.z, qb.z, s1);
        s0 = dot2(qa.w, qa.w, s0);
        s1 = dot2(qb.w, qb.w, s1);
        sc[25] = s0 + s1;
    }

    // softmax
    float mx = sc[0];
#pragma unroll
    for (int i = 1; i < NS; ++i) mx = fmaxf(mx, sc[i]);
    float ssum = 0.f;
#pragma unroll
    for (int i = 0; i < NS; ++i) { sc[i] = __expf(sc[i] - mx); ssum += sc[i]; }
    const float inv = 1.0f / ssum;
#pragma unroll
    for (int i = 0; i < NS; ++i) sc[i] *= inv;

    // ---- u16 fixed-point attn -> LDS (reuse sKp), combine, store ----
    __syncthreads();                      // all k reads done before overwrite
    unsigned int* sP = (unsigned int*)sKp;
    {
        unsigned int* myrow = sP + (wv * 64 + lane) * 13;
#pragma unroll
        for (int j = 0; j < 13; ++j) {
            const unsigned int ulo = (unsigned int)(sc[2 * j] * 65535.f + 0.5f);
            const unsigned int uhi = (unsigned int)(sc[2 * j + 1] * 65535.f + 0.5f);
            myrow[j] = ulo | (uhi << 16);
        }
    }
    __syncthreads();

    const size_t ob = ((size_t)(b * Hn + y0) * Wn + x0) * NS;
    for (int idx = tid; idx < 64 * 13; idx += 256) {
        const int px = idx / 13;
        const int p  = idx - px * 13;
        const unsigned int u0 = sP[(0 * 64 + px) * 13 + p];
        const unsigned int u1 = sP[(1 * 64 + px) * 13 + p];
        const unsigned int u2 = sP[(2 * 64 + px) * 13 + p];
        const unsigned int u3 = sP[(3 * 64 + px) * 13 + p];
        const float lo = (float)((u0 & 0xffffu) + (u1 & 0xffffu) +
                                 (u2 & 0xffffu) + (u3 & 0xffffu));
        const float hi = (float)((u0 >> 16) + (u1 >> 16) + (u2 >> 16) + (u3 >> 16));
        const float k = 1.f / (4.f * 65535.f);
        const int r = px >> 3;
        const int c = px & 7;
        *(float2*)(out + ob + (size_t)r * (Wn * NS) + c * NS + 2 * p) =
            make_float2(lo * k, hi * k);
    }
}

// ================= fallback: R4 monolithic (needs only 16 KB ws) ==========
#define TILE 8
#define HALO 12
#define NHALO (HALO * HALO)
#define PXW 36
__global__ __launch_bounds__(256, 4)
void local_attn_fused_r4(const float* __restrict__ mainp,
                         const float* __restrict__ refp,
                         const unsigned int* __restrict__ wp,
                         float* __restrict__ out)
{
    __shared__ unsigned int sK[NHALO * PXW];
    const int tid  = threadIdx.x;
    const int lane = tid & 63;
    const int wv   = tid >> 6;
    const int head = __builtin_amdgcn_readfirstlane(wv);
    const int b    = blockIdx.z;
    const int y0   = blockIdx.y * TILE;
    const int x0   = blockIdx.x * TILE;
    const unsigned int* wmh = wp + head * (32 * Dn);
    const unsigned int* wrh = wp + 2048 + head * (32 * Dn);
    for (int p = lane; p < NHALO; p += 64) {
        const int hr = p / HALO;
        const int hc = p - hr * HALO;
        const int gy = y0 - 2 + hr;
        const int gx = x0 - 2 + hc;
        float acc[Dn];
#pragma unroll
        for (int d = 0; d < Dn; ++d) acc[d] = 0.f;
        if ((unsigned)gy < (unsigned)Hn && (unsigned)gx < (unsigned)Wn) {
            const float4* rp4 = (const float4*)(refp + (((size_t)b * Hn + gy) * Wn + gx) * Cn);
#pragma unroll
            for (int c4 = 0; c4 < Cn / 4; ++c4) {
                const float4 rv = rp4[c4];
                const unsigned int r01 = pkf16(rv.x, rv.y);
                const unsigned int r23 = pkf16(rv.z, rv.w);
                const unsigned int* w0 = wrh + (2 * c4) * Dn;
                const unsigned int* w1 = wrh + (2 * c4 + 1) * Dn;
#pragma unroll
                for (int d = 0; d < Dn; ++d) acc[d] = dot2(r01, w0[d], acc[d]);
#pragma unroll
                for (int d = 0; d < Dn; ++d) acc[d] = dot2(r23, w1[d], acc[d]);
            }
        }
        unsigned int pk[8];
#pragma unroll
        for (int j = 0; j < 8; ++j) pk[j] = pkf16(acc[2 * j], acc[2 * j + 1]);
        unsigned int* dst = sK + p * PXW + head * 8;
        *(uint4*)(dst)     = make_uint4(pk[0], pk[1], pk[2], pk[3]);
        *(uint4*)(dst + 4) = make_uint4(pk[4], pk[5], pk[6], pk[7]);
    }
    const int pr = lane >> 3;
    const int pc = lane & 7;
    const float4* mp4 = (const float4*)(mainp + (((size_t)b * Hn + (y0 + pr)) * Wn + (x0 + pc)) * Cn);
    float q[Dn];
#pragma unroll
    for (int d = 0; d < Dn; ++d) q[d] = 0.f;
#pragma unroll
    for (int c4 = 0; c4 < Cn / 4; ++c4) {
        const float4 mv = mp4[c4];
        const unsigned int m01 = pkf16(mv.x, mv.y);
        const unsigned int m23 = pkf16(mv.z, mv.w);
        const unsigned int* w0 = wmh + (2 * c4) * Dn;
        const unsigned int* w1 = wmh + (2 * c4 + 1) * Dn;
#pragma unroll
        for (int d = 0; d < Dn; ++d) q[d] = dot2(m01, w0[d], q[d]);
#pragma unroll
        for (int d = 0; d < Dn; ++d) q[d] = dot2(m23, w1[d], q[d]);
    }
    unsigned int qh[8];
#pragma unroll
    for (int j = 0; j < 8; ++j) qh[j] = pkf16(q[2 * j], q[2 * j + 1]);
    __syncthreads();
    float sc[NS];
#pragma unroll
    for (int di = 0; di < 5; ++di) {
#pragma unroll
        for (int dj = 0; dj < 5; ++dj) {
            const int h = (pr + di) * HALO + (pc + dj);
            const unsigned int* src = sK + h * PXW + head * 8;
            const uint4 ka = *(const uint4*)(src);
            const uint4 kb = *(const uint4*)(src + 4);
            float s;
            s = dot2(qh[0], ka.x, 0.f);
            s = dot2(qh[1], ka.y, s);
            s = dot2(qh[2], ka.z, s);
            s = dot2(qh[3], ka.w, s);
            s = dot2(qh[4], kb.x, s);
            s = dot2(qh[5], kb.y, s);
            s = dot2(qh[6], kb.z, s);
            s = dot2(qh[7], kb.w, s);
            sc[di * 5 + dj] = s;
        }
    }
    {
        float s = q[0] * q[0];
#pragma unroll
        for (int d = 1; d < Dn; ++d) s = fmaf(q[d], q[d], s);
        sc[25] = s;
    }
    float mx = sc[0];
#pragma unroll
    for (int i = 1; i < NS; ++i) mx = fmaxf(mx, sc[i]);
    float ssum = 0.f;
#pragma unroll
    for (int i = 0; i < NS; ++i) { sc[i] = __expf(sc[i] - mx); ssum += sc[i]; }
    const float inv = 1.0f / ssum;
#pragma unroll
    for (int i = 0; i < NS; ++i) sc[i] *= inv;
    __syncthreads();
    {
        unsigned int* myrow = sK + (wv * 64 + lane) * 14;
#pragma unroll
        for (int j = 0; j < 13; ++j) myrow[j] = pkf16(sc[2 * j], sc[2 * j + 1]);
    }
    __syncthreads();
    const unsigned short* sA = (const unsigned short*)sK;
    const size_t obase = (((size_t)b * Hn + y0) * Wn + x0) * NS;
    for (int idx = tid; idx < TILE * TILE * NS; idx += 256) {
        const int r   = idx / (TILE * NS);
        const int t   = idx - r * (TILE * NS);
        const int c   = t / NS;
        const int i   = t - c * NS;
        const int ppx = r * TILE + c;
        float acc = 0.f;
#pragma unroll
        for (int h = 0; h < 4; ++h)
            acc += (float)__builtin_bit_cast(_Float16, sA[(h * 64 + ppx) * 28 + i]);
        out[obase + (size_t)r * (Wn * NS) + t] = 0.25f * acc;
    }
}

extern "C" void kernel_launch(void* const* d_in, const int* in_sizes, int n_in,
                              void* d_out, int out_size, void* d_ws, size_t ws_size,
                              hipStream_t stream) {
    (void)in_sizes; (void)n_in; (void)out_size;
    const float* mainp = (const float*)d_in[0];
    const float* refp  = (const float*)d_in[1];
    const float* Wm    = (const float*)d_in[2];
    const float* Wr    = (const float*)d_in[3];
    unsigned int* wpk  = (unsigned int*)d_ws;
    float* out = (float*)d_out;

    pack_weights<<<16, 256, 0, stream>>>(Wm, Wr, wpk);
    if (ws_size >= WS_NEEDED) {
        uint4* wsQ = (uint4*)((char*)d_ws + WS_Q_OFF_B);
        uint4* wsK = (uint4*)((char*)d_ws + WS_K_OFF_B);
        proj_qk<<<NPX / 64, 256, 0, stream>>>(mainp, refp, wpk, wsQ, wsK);
        dim3 grid2(Wn / 8, Hn / 8, Bn);                // 16 x 16 x 8 = 2048
        attn_scores<<<grid2, 256, 0, stream>>>(wsQ, wsK, out);
    } else {
        dim3 grid2(Wn / TILE, Hn / TILE, Bn);
        local_attn_fused_r4<<<grid2, 256, 0, stream>>>(mainp, refp, wpk, out);
    }
}